// Round 4
// baseline (1575.475 us; speedup 1.0000x reference)
//
#include <hip/hip_runtime.h>
#include <stdint.h>

#define NN 100000
#define D 128
#define W0 128                         // nodes per bucket (power of 2)
#define NB ((NN + W0 - 1) / W0)        // 782 buckets
#define C1 8192                        // edges per block, partition passes

// ---- workspace layout (bytes) ----
static const size_t O_FLAG   = 0;                      // detect flag
static const size_t O_BCNT   = 256;                    // NB ints (bucket counts)
static const size_t O_BSTART = O_BCNT + 4096;          // NB+1 ints
static const size_t O_BCUR   = O_BSTART + 4096;        // NB ints
static const size_t O_WTL    = O_BCUR + 4096;
static const size_t O_WTR    = O_WTL + (size_t)D * D * 4;
static const size_t O_DEG    = O_WTR + (size_t)D * D * 4;   // Plan B only
static const size_t O_RECS   = O_DEG + (size_t)NN * 4;      // E packed records

// Detect whether edge_index buffer is int64 (odd int32 words zero) or int32.
__global__ void k_detect(const int* __restrict__ ei, int* flag) {
    if (threadIdx.x == 0 && blockIdx.x == 0) {
        int ok = 1;
        for (int j = 0; j < 128; ++j)
            if (ei[2 * j + 1] != 0) { ok = 0; break; }
        *flag = ok;
    }
}

__device__ __forceinline__ int edge_at(const int* ei, long long pos, int is64) {
    return is64 ? ei[2 * pos] : ei[pos];
}

// Transpose both weight matrices: Wt[k][o] = W[o][k]
__global__ void k_transpose(const float* __restrict__ Wl, const float* __restrict__ Wr,
                            float* __restrict__ WtL, float* __restrict__ WtR) {
    int t = blockIdx.x * 256 + threadIdx.x;
    if (t < D * D) {
        int o = t >> 7, k = t & 127;
        WtL[k * D + o] = Wl[t];
        WtR[k * D + o] = Wr[t];
    }
}

// Pass 1a: per-block LDS bucket histogram -> one global atomic per bucket/block.
__global__ __launch_bounds__(256) void k_p1count(const int* __restrict__ ei,
                                                 const int* __restrict__ flag,
                                                 int* __restrict__ bcount, long long E) {
    __shared__ int cnt[NB];
    for (int i = threadIdx.x; i < NB; i += 256) cnt[i] = 0;
    __syncthreads();
    int is64 = *flag;
    long long base = (long long)blockIdx.x * C1;
    for (int j = threadIdx.x; j < C1; j += 256) {
        long long e = base + j;
        if (e < E) {
            int d = edge_at(ei, E + e, is64);
            atomicAdd(&cnt[d >> 7], 1);
        }
    }
    __syncthreads();
    for (int i = threadIdx.x; i < NB; i += 256) {
        int c = cnt[i];
        if (c) atomicAdd(&bcount[i], c);
    }
}

// Exclusive scan of NB bucket counts (single block).
__global__ __launch_bounds__(1024) void k_bscan(const int* __restrict__ bcount,
                                                int* __restrict__ bstart,
                                                int* __restrict__ bcur) {
    __shared__ int sh[1024];
    int t = threadIdx.x;
    sh[t] = (t < NB) ? bcount[t] : 0;
    __syncthreads();
    for (int d = 1; d < 1024; d <<= 1) {
        int v = (t >= d) ? sh[t - d] : 0;
        __syncthreads();
        sh[t] += v;
        __syncthreads();
    }
    if (t < NB) {
        int ex = (t > 0) ? sh[t - 1] : 0;
        bstart[t] = ex;
        bcur[t] = ex;
    }
    if (t == NB - 1) bstart[NB] = sh[NB - 1];
}

// Pass 1b: scatter packed records (src | d_local<<20) into bucket regions.
// Per-block LDS rank counters; one global cursor atomic per bucket per block.
__global__ __launch_bounds__(256) void k_p1scatter(const int* __restrict__ ei,
                                                   const int* __restrict__ flag,
                                                   int* __restrict__ bcur,
                                                   unsigned int* __restrict__ recs,
                                                   long long E) {
    __shared__ int cnt[NB];
    __shared__ int rbase[NB];
    for (int i = threadIdx.x; i < NB; i += 256) cnt[i] = 0;
    __syncthreads();
    int is64 = *flag;
    long long base = (long long)blockIdx.x * C1;
    for (int j = threadIdx.x; j < C1; j += 256) {
        long long e = base + j;
        if (e < E) {
            int d = edge_at(ei, E + e, is64);
            atomicAdd(&cnt[d >> 7], 1);
        }
    }
    __syncthreads();
    for (int i = threadIdx.x; i < NB; i += 256) {
        int c = cnt[i];
        rbase[i] = c ? atomicAdd(&bcur[i], c) : 0;
    }
    __syncthreads();
    for (int i = threadIdx.x; i < NB; i += 256) cnt[i] = 0;
    __syncthreads();
    for (int j = threadIdx.x; j < C1; j += 256) {
        long long e = base + j;
        if (e < E) {
            int s = edge_at(ei, e, is64);
            int d = edge_at(ei, E + e, is64);
            int bu = d >> 7;
            int pos = rbase[bu] + atomicAdd(&cnt[bu], 1);
            recs[pos] = (unsigned)s | ((unsigned)(d & (W0 - 1)) << 20);
        }
    }
}

// Aggregation: one block per bucket. LDS accumulator 128 nodes x 128 dims (64 KB)
// + LDS degree counters. Wave gathers x[src] rows (stride-1 dword loads ->
// conflict-free ds_add_f32 at 2 lanes/bank), then dense mean writeout.
__global__ __launch_bounds__(256) void k_aggb(const float* __restrict__ x,
                                              const unsigned int* __restrict__ recs,
                                              const int* __restrict__ bstart,
                                              float* __restrict__ out, int N) {
    __shared__ float acc[W0 * D];
    __shared__ int cnt[W0];
    int t = threadIdx.x;
    for (int i = t; i < W0 * D / 4; i += 256) {
        float4 z; z.x = 0.f; z.y = 0.f; z.z = 0.f; z.w = 0.f;
        ((float4*)acc)[i] = z;
    }
    for (int i = t; i < W0; i += 256) cnt[i] = 0;
    __syncthreads();

    int bu = blockIdx.x;
    int e0 = bstart[bu], e1 = bstart[bu + 1];
    int lane = t & 63;
    int wv = t >> 6;
    int total = e1 - e0;
    int per = (total + 3) >> 2;
    int a0 = e0 + wv * per;
    int a1 = a0 + per; if (a1 > e1) a1 = e1;
    int e = a0;
    for (; e + 4 <= a1; e += 4) {
        unsigned r0 = recs[e], r1 = recs[e + 1], r2 = recs[e + 2], r3 = recs[e + 3];
        const float* p0 = x + (long long)(r0 & 0xFFFFFu) * D;
        const float* p1 = x + (long long)(r1 & 0xFFFFFu) * D;
        const float* p2 = x + (long long)(r2 & 0xFFFFFu) * D;
        const float* p3 = x + (long long)(r3 & 0xFFFFFu) * D;
        float g0x = p0[lane], g0y = p0[64 + lane];
        float g1x = p1[lane], g1y = p1[64 + lane];
        float g2x = p2[lane], g2y = p2[64 + lane];
        float g3x = p3[lane], g3y = p3[64 + lane];
        int o0 = (int)(r0 >> 20) * D, o1 = (int)(r1 >> 20) * D;
        int o2 = (int)(r2 >> 20) * D, o3 = (int)(r3 >> 20) * D;
        atomicAdd(&acc[o0 + lane], g0x); atomicAdd(&acc[o0 + 64 + lane], g0y);
        atomicAdd(&acc[o1 + lane], g1x); atomicAdd(&acc[o1 + 64 + lane], g1y);
        atomicAdd(&acc[o2 + lane], g2x); atomicAdd(&acc[o2 + 64 + lane], g2y);
        atomicAdd(&acc[o3 + lane], g3x); atomicAdd(&acc[o3 + 64 + lane], g3y);
        if (lane == 0) {
            atomicAdd(&cnt[r0 >> 20], 1); atomicAdd(&cnt[r1 >> 20], 1);
            atomicAdd(&cnt[r2 >> 20], 1); atomicAdd(&cnt[r3 >> 20], 1);
        }
    }
    for (; e < a1; ++e) {
        unsigned r = recs[e];
        const float* p = x + (long long)(r & 0xFFFFFu) * D;
        float gx = p[lane], gy = p[64 + lane];
        int o = (int)(r >> 20) * D;
        atomicAdd(&acc[o + lane], gx); atomicAdd(&acc[o + 64 + lane], gy);
        if (lane == 0) atomicAdd(&cnt[r >> 20], 1);
    }
    __syncthreads();

    int nbase = bu * W0;
    for (int idx = t; idx < W0 * 32; idx += 256) {
        int row = idx >> 5;
        int node = nbase + row;
        if (node < N) {
            float inv = 1.0f / fmaxf((float)cnt[row], 1.0f);
            float4 v = ((const float4*)acc)[idx];
            v.x *= inv; v.y *= inv; v.z *= inv; v.w *= inv;
            ((float4*)out)[(long long)node * 32 + (idx & 31)] = v;
        }
    }
}

// Plan B: atomic scatter (one wave per edge) then mean.
__global__ __launch_bounds__(256) void k_scatterB(const float* __restrict__ x,
                                                  const int* __restrict__ ei,
                                                  const int* __restrict__ flag,
                                                  float* out, float* deg, long long E) {
    int lane = threadIdx.x & 63;
    long long e = (long long)blockIdx.x * 4 + (threadIdx.x >> 6);
    if (e >= E) return;
    int is64 = *flag;
    int s = edge_at(ei, e, is64);
    int d = edge_at(ei, E + e, is64);
    atomicAdd(&out[(long long)d * D + lane], x[(long long)s * D + lane]);
    atomicAdd(&out[(long long)d * D + 64 + lane], x[(long long)s * D + 64 + lane]);
    if (lane == 0) atomicAdd(&deg[d], 1.0f);
}

__global__ void k_meanB(float* out, const float* __restrict__ deg) {
    long long i = (long long)blockIdx.x * 256 + threadIdx.x;
    if (i >= (long long)NN * D) return;
    out[i] *= 1.0f / fmaxf(deg[i >> 7], 1.0f);
}

// Fused out = agg@Wl^T + b + x@Wr^T, then row L2-normalize.
// Block = 256 threads -> 64-row x 128-col tile. Thread = 4 rows x 8 cols.
__global__ __launch_bounds__(256) void k_gemm(const float* __restrict__ x,
                                              const float* agg,
                                              const float* __restrict__ WtL,
                                              const float* __restrict__ WtR,
                                              const float* __restrict__ bl,
                                              float* out, int N) {
    __shared__ float Bs[D * D];   // 64 KB: W^T tile, [k][col]
    int t = threadIdx.x;
    int tx = t & 15;
    int ty = t >> 4;
    int row0 = blockIdx.x * 64 + ty * 4;
    int c0 = tx * 8;

    float acc[4][8];
    float4 b0 = *(const float4*)(bl + c0);
    float4 b1 = *(const float4*)(bl + c0 + 4);
#pragma unroll
    for (int r = 0; r < 4; ++r) {
        acc[r][0] = b0.x; acc[r][1] = b0.y; acc[r][2] = b0.z; acc[r][3] = b0.w;
        acc[r][4] = b1.x; acc[r][5] = b1.y; acc[r][6] = b1.z; acc[r][7] = b1.w;
    }

    long long rws[4];
#pragma unroll
    for (int r = 0; r < 4; ++r) {
        int rr = row0 + r;
        rws[r] = (rr < N) ? (long long)rr : (long long)(N - 1);
    }

    for (int phase = 0; phase < 2; ++phase) {
        const float* A = phase ? x : agg;
        const float* W = phase ? WtR : WtL;
        if (phase) __syncthreads();   // phase-0 LDS reads + in-place agg reads done
#pragma unroll
        for (int i = 0; i < 16; ++i) {
            int idx = t + i * 256;
            ((float4*)Bs)[idx] = ((const float4*)W)[idx];
        }
        __syncthreads();

        const float4* Ar0 = (const float4*)(A + rws[0] * D);
        const float4* Ar1 = (const float4*)(A + rws[1] * D);
        const float4* Ar2 = (const float4*)(A + rws[2] * D);
        const float4* Ar3 = (const float4*)(A + rws[3] * D);

#pragma unroll 2
        for (int k4 = 0; k4 < 32; ++k4) {
            float4 av[4];
            av[0] = Ar0[k4]; av[1] = Ar1[k4]; av[2] = Ar2[k4]; av[3] = Ar3[k4];
#pragma unroll
            for (int kk = 0; kk < 4; ++kk) {
                int k = k4 * 4 + kk;
                float4 w0 = *(const float4*)&Bs[k * D + c0];
                float4 w1 = *(const float4*)&Bs[k * D + c0 + 4];
#pragma unroll
                for (int r = 0; r < 4; ++r) {
                    float a = (kk == 0) ? av[r].x : (kk == 1) ? av[r].y
                             : (kk == 2) ? av[r].z : av[r].w;
                    acc[r][0] = fmaf(a, w0.x, acc[r][0]);
                    acc[r][1] = fmaf(a, w0.y, acc[r][1]);
                    acc[r][2] = fmaf(a, w0.z, acc[r][2]);
                    acc[r][3] = fmaf(a, w0.w, acc[r][3]);
                    acc[r][4] = fmaf(a, w1.x, acc[r][4]);
                    acc[r][5] = fmaf(a, w1.y, acc[r][5]);
                    acc[r][6] = fmaf(a, w1.z, acc[r][6]);
                    acc[r][7] = fmaf(a, w1.w, acc[r][7]);
                }
            }
        }
    }

#pragma unroll
    for (int r = 0; r < 4; ++r) {
        float s = 0.f;
#pragma unroll
        for (int j = 0; j < 8; ++j) s = fmaf(acc[r][j], acc[r][j], s);
        s += __shfl_xor(s, 1, 64);
        s += __shfl_xor(s, 2, 64);
        s += __shfl_xor(s, 4, 64);
        s += __shfl_xor(s, 8, 64);
        float scale = 1.0f / fmaxf(sqrtf(s), 1e-12f);
        int rr = row0 + r;
        if (rr < N) {
            float4 v0, v1;
            v0.x = acc[r][0] * scale; v0.y = acc[r][1] * scale;
            v0.z = acc[r][2] * scale; v0.w = acc[r][3] * scale;
            v1.x = acc[r][4] * scale; v1.y = acc[r][5] * scale;
            v1.z = acc[r][6] * scale; v1.w = acc[r][7] * scale;
            float4* op = (float4*)(out + (long long)rr * D + c0);
            op[0] = v0; op[1] = v1;
        }
    }
}

extern "C" void kernel_launch(void* const* d_in, const int* in_sizes, int n_in,
                              void* d_out, int out_size, void* d_ws, size_t ws_size,
                              hipStream_t stream) {
    const float* x  = (const float*)d_in[0];
    const int*   ei = (const int*)d_in[1];
    const float* Wl = (const float*)d_in[2];
    const float* bl = (const float*)d_in[3];
    const float* Wr = (const float*)d_in[4];
    float* out = (float*)d_out;
    const long long E = (long long)in_sizes[1] / 2;

    char* ws = (char*)d_ws;
    int*      flag   = (int*)(ws + O_FLAG);
    int*      bcount = (int*)(ws + O_BCNT);
    int*      bstart = (int*)(ws + O_BSTART);
    int*      bcur   = (int*)(ws + O_BCUR);
    float*    WtL    = (float*)(ws + O_WTL);
    float*    WtR    = (float*)(ws + O_WTR);
    float*    deg    = (float*)(ws + O_DEG);
    unsigned* recs   = (unsigned*)(ws + O_RECS);

    size_t planA_bytes = O_RECS + (size_t)E * 4;
    bool planA = ws_size >= planA_bytes;

    k_detect<<<1, 64, 0, stream>>>(ei, flag);
    k_transpose<<<(D * D + 255) / 256, 256, 0, stream>>>(Wl, Wr, WtL, WtR);

    if (planA) {
        int pblocks = (int)((E + C1 - 1) / C1);
        hipMemsetAsync(ws + O_BCNT, 0, (size_t)NB * 4, stream);
        k_p1count<<<pblocks, 256, 0, stream>>>(ei, flag, bcount, E);
        k_bscan<<<1, 1024, 0, stream>>>(bcount, bstart, bcur);
        k_p1scatter<<<pblocks, 256, 0, stream>>>(ei, flag, bcur, recs, E);
        k_aggb<<<NB, 256, 0, stream>>>(x, recs, bstart, out, NN);
    } else {
        hipMemsetAsync(out, 0, (size_t)NN * D * 4, stream);
        hipMemsetAsync(ws + O_DEG, 0, (size_t)NN * 4, stream);
        k_scatterB<<<(int)((E + 3) / 4), 256, 0, stream>>>(x, ei, flag, out, deg, E);
        k_meanB<<<(int)(((long long)NN * D + 255) / 256), 256, 0, stream>>>(out, deg);
    }
    k_gemm<<<(NN + 63) / 64, 256, 0, stream>>>(x, out, WtL, WtR, bl, out, NN);
}

// Round 5
// 378.059 us; speedup vs baseline: 4.1673x; 4.1673x over previous
//
#include <hip/hip_runtime.h>
#include <stdint.h>

#define NN 100000
#define D 128
#define W0 128                         // nodes per bucket (power of 2)
#define NB ((NN + W0 - 1) / W0)        // 782 buckets
#define C1 8192                        // edges per block, partition passes

// ---- workspace layout (bytes) ----
static const size_t O_FLAG   = 0;                      // detect flag
static const size_t O_BCNT   = 256;                    // NB ints (bucket counts)
static const size_t O_BSTART = O_BCNT + 4096;          // NB+1 ints
static const size_t O_BCUR   = O_BSTART + 4096;        // NB ints
static const size_t O_WTL    = O_BCUR + 4096;
static const size_t O_WTR    = O_WTL + (size_t)D * D * 4;
static const size_t O_OFFS   = O_WTR + (size_t)D * D * 4;    // NN+1 ints
static const size_t O_DEG    = O_OFFS + (size_t)(NN + 64) * 4;  // Plan B only
static const size_t O_RECS   = O_DEG + (size_t)NN * 4;       // E packed records
// O_SRCS = O_RECS + E*4 (computed at launch)

// Detect whether edge_index buffer is int64 (odd int32 words zero) or int32.
__global__ void k_detect(const int* __restrict__ ei, int* flag) {
    if (threadIdx.x == 0 && blockIdx.x == 0) {
        int ok = 1;
        for (int j = 0; j < 128; ++j)
            if (ei[2 * j + 1] != 0) { ok = 0; break; }
        *flag = ok;
    }
}

__device__ __forceinline__ int edge_at(const int* ei, long long pos, int is64) {
    return is64 ? ei[2 * pos] : ei[pos];
}

// Transpose both weight matrices: Wt[k][o] = W[o][k]
__global__ void k_transpose(const float* __restrict__ Wl, const float* __restrict__ Wr,
                            float* __restrict__ WtL, float* __restrict__ WtR) {
    int t = blockIdx.x * 256 + threadIdx.x;
    if (t < D * D) {
        int o = t >> 7, k = t & 127;
        WtL[k * D + o] = Wl[t];
        WtR[k * D + o] = Wr[t];
    }
}

// Pass 1a: per-block LDS bucket histogram -> one global atomic per bucket/block.
__global__ __launch_bounds__(256) void k_p1count(const int* __restrict__ ei,
                                                 const int* __restrict__ flag,
                                                 int* __restrict__ bcount, long long E) {
    __shared__ int cnt[NB];
    for (int i = threadIdx.x; i < NB; i += 256) cnt[i] = 0;
    __syncthreads();
    int is64 = *flag;
    long long base = (long long)blockIdx.x * C1;
    for (int j = threadIdx.x; j < C1; j += 256) {
        long long e = base + j;
        if (e < E) {
            int d = edge_at(ei, E + e, is64);
            atomicAdd(&cnt[d >> 7], 1);
        }
    }
    __syncthreads();
    for (int i = threadIdx.x; i < NB; i += 256) {
        int c = cnt[i];
        if (c) atomicAdd(&bcount[i], c);
    }
}

// Exclusive scan of NB bucket counts (single block). Also writes offs[NN] = E.
__global__ __launch_bounds__(1024) void k_bscan(const int* __restrict__ bcount,
                                                int* __restrict__ bstart,
                                                int* __restrict__ bcur,
                                                int* __restrict__ offs) {
    __shared__ int sh[1024];
    int t = threadIdx.x;
    sh[t] = (t < NB) ? bcount[t] : 0;
    __syncthreads();
    for (int d = 1; d < 1024; d <<= 1) {
        int v = (t >= d) ? sh[t - d] : 0;
        __syncthreads();
        sh[t] += v;
        __syncthreads();
    }
    if (t < NB) {
        int ex = (t > 0) ? sh[t - 1] : 0;
        bstart[t] = ex;
        bcur[t] = ex;
    }
    if (t == NB - 1) {
        bstart[NB] = sh[NB - 1];
        offs[NN] = sh[NB - 1];     // total edge count = CSR sentinel
    }
}

// Pass 1b: scatter packed records (src | d_local<<20) into bucket regions.
// Per-block LDS rank counters; one global cursor atomic per bucket per block.
__global__ __launch_bounds__(256) void k_p1scatter(const int* __restrict__ ei,
                                                   const int* __restrict__ flag,
                                                   int* __restrict__ bcur,
                                                   unsigned int* __restrict__ recs,
                                                   long long E) {
    __shared__ int cnt[NB];
    __shared__ int rbase[NB];
    for (int i = threadIdx.x; i < NB; i += 256) cnt[i] = 0;
    __syncthreads();
    int is64 = *flag;
    long long base = (long long)blockIdx.x * C1;
    for (int j = threadIdx.x; j < C1; j += 256) {
        long long e = base + j;
        if (e < E) {
            int d = edge_at(ei, E + e, is64);
            atomicAdd(&cnt[d >> 7], 1);
        }
    }
    __syncthreads();
    for (int i = threadIdx.x; i < NB; i += 256) {
        int c = cnt[i];
        rbase[i] = c ? atomicAdd(&bcur[i], c) : 0;
    }
    __syncthreads();
    for (int i = threadIdx.x; i < NB; i += 256) cnt[i] = 0;
    __syncthreads();
    for (int j = threadIdx.x; j < C1; j += 256) {
        long long e = base + j;
        if (e < E) {
            int s = edge_at(ei, e, is64);
            int d = edge_at(ei, E + e, is64);
            int bu = d >> 7;
            int pos = rbase[bu] + atomicAdd(&cnt[bu], 1);
            recs[pos] = (unsigned)s | ((unsigned)(d & (W0 - 1)) << 20);
        }
    }
}

// Pass 2: per bucket, bucket-sorted records -> exact per-node CSR.
// All reads/writes confined to this bucket's ~8 KB region (L2-resident).
__global__ __launch_bounds__(256) void k_p2(const unsigned int* __restrict__ recs,
                                            const int* __restrict__ bstart,
                                            int* __restrict__ offs,
                                            int* __restrict__ srcs, int N) {
    __shared__ int cnt[W0];
    __shared__ int off[W0];
    int t = threadIdx.x;
    int bu = blockIdx.x;
    int e0 = bstart[bu], e1 = bstart[bu + 1];
    if (t < W0) cnt[t] = 0;
    __syncthreads();
    for (int e = e0 + t; e < e1; e += 256)
        atomicAdd(&cnt[recs[e] >> 20], 1);
    __syncthreads();
    if (t < W0) off[t] = cnt[t];
    __syncthreads();
    for (int d = 1; d < W0; d <<= 1) {
        int v = 0;
        if (t < W0 && t >= d) v = off[t - d];
        __syncthreads();
        if (t < W0) off[t] += v;
        __syncthreads();
    }
    if (t < W0) {
        int ex = (t > 0) ? off[t - 1] : 0;
        int node = bu * W0 + t;
        if (node < N) offs[node] = e0 + ex;
        cnt[t] = e0 + ex;              // reuse as global write cursor
    }
    __syncthreads();
    for (int e = e0 + t; e < e1; e += 256) {
        unsigned r = recs[e];
        int pos = atomicAdd(&cnt[r >> 20], 1);
        srcs[pos] = (int)(r & 0xFFFFFu);
    }
}

// One wave per node: mean-aggregate neighbor rows into agg (= d_out).
__global__ __launch_bounds__(256) void k_agg(const float* __restrict__ x,
                                             const int* __restrict__ offs,
                                             const int* __restrict__ srcs,
                                             float* agg, int N) {
    int lane = threadIdx.x & 63;
    int wid = __builtin_amdgcn_readfirstlane(threadIdx.x >> 6);
    int node = blockIdx.x * 4 + wid;
    if (node >= N) return;
    int e0 = offs[node], e1 = offs[node + 1];
    const float2* x2 = (const float2*)x;
    float ax = 0.f, ay = 0.f;
    int e = e0;
    for (; e + 4 <= e1; e += 4) {
        int s0 = srcs[e], s1 = srcs[e + 1], s2 = srcs[e + 2], s3 = srcs[e + 3];
        float2 v0 = x2[(long long)s0 * 64 + lane];
        float2 v1 = x2[(long long)s1 * 64 + lane];
        float2 v2 = x2[(long long)s2 * 64 + lane];
        float2 v3 = x2[(long long)s3 * 64 + lane];
        ax += v0.x + v1.x + v2.x + v3.x;
        ay += v0.y + v1.y + v2.y + v3.y;
    }
    for (; e < e1; ++e) {
        int s = srcs[e];
        float2 v = x2[(long long)s * 64 + lane];
        ax += v.x; ay += v.y;
    }
    float inv = 1.0f / fmaxf((float)(e1 - e0), 1.0f);
    float2 o; o.x = ax * inv; o.y = ay * inv;
    ((float2*)agg)[(long long)node * 64 + lane] = o;
}

// Plan B: atomic scatter (one wave per edge) then mean.
__global__ __launch_bounds__(256) void k_scatterB(const float* __restrict__ x,
                                                  const int* __restrict__ ei,
                                                  const int* __restrict__ flag,
                                                  float* out, float* deg, long long E) {
    int lane = threadIdx.x & 63;
    long long e = (long long)blockIdx.x * 4 + (threadIdx.x >> 6);
    if (e >= E) return;
    int is64 = *flag;
    int s = edge_at(ei, e, is64);
    int d = edge_at(ei, E + e, is64);
    atomicAdd(&out[(long long)d * D + lane], x[(long long)s * D + lane]);
    atomicAdd(&out[(long long)d * D + 64 + lane], x[(long long)s * D + 64 + lane]);
    if (lane == 0) atomicAdd(&deg[d], 1.0f);
}

__global__ void k_meanB(float* out, const float* __restrict__ deg) {
    long long i = (long long)blockIdx.x * 256 + threadIdx.x;
    if (i >= (long long)NN * D) return;
    out[i] *= 1.0f / fmaxf(deg[i >> 7], 1.0f);
}

// Fused out = agg@Wl^T + b + x@Wr^T, then row L2-normalize.
// Block = 256 threads -> 64-row x 128-col tile. Thread = 4 rows x 8 cols.
__global__ __launch_bounds__(256) void k_gemm(const float* __restrict__ x,
                                              const float* agg,
                                              const float* __restrict__ WtL,
                                              const float* __restrict__ WtR,
                                              const float* __restrict__ bl,
                                              float* out, int N) {
    __shared__ float Bs[D * D];   // 64 KB: W^T tile, [k][col]
    int t = threadIdx.x;
    int tx = t & 15;
    int ty = t >> 4;
    int row0 = blockIdx.x * 64 + ty * 4;
    int c0 = tx * 8;

    float acc[4][8];
    float4 b0 = *(const float4*)(bl + c0);
    float4 b1 = *(const float4*)(bl + c0 + 4);
#pragma unroll
    for (int r = 0; r < 4; ++r) {
        acc[r][0] = b0.x; acc[r][1] = b0.y; acc[r][2] = b0.z; acc[r][3] = b0.w;
        acc[r][4] = b1.x; acc[r][5] = b1.y; acc[r][6] = b1.z; acc[r][7] = b1.w;
    }

    long long rws[4];
#pragma unroll
    for (int r = 0; r < 4; ++r) {
        int rr = row0 + r;
        rws[r] = (rr < N) ? (long long)rr : (long long)(N - 1);
    }

    for (int phase = 0; phase < 2; ++phase) {
        const float* A = phase ? x : agg;
        const float* W = phase ? WtR : WtL;
        if (phase) __syncthreads();   // phase-0 LDS reads + in-place agg reads done
#pragma unroll
        for (int i = 0; i < 16; ++i) {
            int idx = t + i * 256;
            ((float4*)Bs)[idx] = ((const float4*)W)[idx];
        }
        __syncthreads();

        const float4* Ar0 = (const float4*)(A + rws[0] * D);
        const float4* Ar1 = (const float4*)(A + rws[1] * D);
        const float4* Ar2 = (const float4*)(A + rws[2] * D);
        const float4* Ar3 = (const float4*)(A + rws[3] * D);

#pragma unroll 2
        for (int k4 = 0; k4 < 32; ++k4) {
            float4 av[4];
            av[0] = Ar0[k4]; av[1] = Ar1[k4]; av[2] = Ar2[k4]; av[3] = Ar3[k4];
#pragma unroll
            for (int kk = 0; kk < 4; ++kk) {
                int k = k4 * 4 + kk;
                float4 w0 = *(const float4*)&Bs[k * D + c0];
                float4 w1 = *(const float4*)&Bs[k * D + c0 + 4];
#pragma unroll
                for (int r = 0; r < 4; ++r) {
                    float a = (kk == 0) ? av[r].x : (kk == 1) ? av[r].y
                             : (kk == 2) ? av[r].z : av[r].w;
                    acc[r][0] = fmaf(a, w0.x, acc[r][0]);
                    acc[r][1] = fmaf(a, w0.y, acc[r][1]);
                    acc[r][2] = fmaf(a, w0.z, acc[r][2]);
                    acc[r][3] = fmaf(a, w0.w, acc[r][3]);
                    acc[r][4] = fmaf(a, w1.x, acc[r][4]);
                    acc[r][5] = fmaf(a, w1.y, acc[r][5]);
                    acc[r][6] = fmaf(a, w1.z, acc[r][6]);
                    acc[r][7] = fmaf(a, w1.w, acc[r][7]);
                }
            }
        }
    }

#pragma unroll
    for (int r = 0; r < 4; ++r) {
        float s = 0.f;
#pragma unroll
        for (int j = 0; j < 8; ++j) s = fmaf(acc[r][j], acc[r][j], s);
        s += __shfl_xor(s, 1, 64);
        s += __shfl_xor(s, 2, 64);
        s += __shfl_xor(s, 4, 64);
        s += __shfl_xor(s, 8, 64);
        float scale = 1.0f / fmaxf(sqrtf(s), 1e-12f);
        int rr = row0 + r;
        if (rr < N) {
            float4 v0, v1;
            v0.x = acc[r][0] * scale; v0.y = acc[r][1] * scale;
            v0.z = acc[r][2] * scale; v0.w = acc[r][3] * scale;
            v1.x = acc[r][4] * scale; v1.y = acc[r][5] * scale;
            v1.z = acc[r][6] * scale; v1.w = acc[r][7] * scale;
            float4* op = (float4*)(out + (long long)rr * D + c0);
            op[0] = v0; op[1] = v1;
        }
    }
}

extern "C" void kernel_launch(void* const* d_in, const int* in_sizes, int n_in,
                              void* d_out, int out_size, void* d_ws, size_t ws_size,
                              hipStream_t stream) {
    const float* x  = (const float*)d_in[0];
    const int*   ei = (const int*)d_in[1];
    const float* Wl = (const float*)d_in[2];
    const float* bl = (const float*)d_in[3];
    const float* Wr = (const float*)d_in[4];
    float* out = (float*)d_out;
    const long long E = (long long)in_sizes[1] / 2;

    char* ws = (char*)d_ws;
    int*      flag   = (int*)(ws + O_FLAG);
    int*      bcount = (int*)(ws + O_BCNT);
    int*      bstart = (int*)(ws + O_BSTART);
    int*      bcur   = (int*)(ws + O_BCUR);
    float*    WtL    = (float*)(ws + O_WTL);
    float*    WtR    = (float*)(ws + O_WTR);
    int*      offs   = (int*)(ws + O_OFFS);
    float*    deg    = (float*)(ws + O_DEG);
    unsigned* recs   = (unsigned*)(ws + O_RECS);
    int*      srcs   = (int*)(ws + O_RECS + (size_t)E * 4);

    size_t planA_bytes = O_RECS + (size_t)E * 8;
    bool planA = ws_size >= planA_bytes;

    k_detect<<<1, 64, 0, stream>>>(ei, flag);
    k_transpose<<<(D * D + 255) / 256, 256, 0, stream>>>(Wl, Wr, WtL, WtR);

    if (planA) {
        int pblocks = (int)((E + C1 - 1) / C1);
        hipMemsetAsync(ws + O_BCNT, 0, (size_t)NB * 4, stream);
        k_p1count<<<pblocks, 256, 0, stream>>>(ei, flag, bcount, E);
        k_bscan<<<1, 1024, 0, stream>>>(bcount, bstart, bcur, offs);
        k_p1scatter<<<pblocks, 256, 0, stream>>>(ei, flag, bcur, recs, E);
        k_p2<<<NB, 256, 0, stream>>>(recs, bstart, offs, srcs, NN);
        k_agg<<<(NN + 3) / 4, 256, 0, stream>>>(x, offs, srcs, out, NN);
    } else {
        hipMemsetAsync(out, 0, (size_t)NN * D * 4, stream);
        hipMemsetAsync(ws + O_DEG, 0, (size_t)NN * 4, stream);
        k_scatterB<<<(int)((E + 3) / 4), 256, 0, stream>>>(x, ei, flag, out, deg, E);
        k_meanB<<<(int)(((long long)NN * D + 255) / 256), 256, 0, stream>>>(out, deg);
    }
    k_gemm<<<(NN + 63) / 64, 256, 0, stream>>>(x, out, WtL, WtR, bl, out, NN);
}

// Round 6
// 366.914 us; speedup vs baseline: 4.2939x; 1.0304x over previous
//
#include <hip/hip_runtime.h>
#include <stdint.h>

#define NN 100000
#define D 128
#define W0 128                         // nodes per bucket (power of 2)
#define NB ((NN + W0 - 1) / W0)        // 782 buckets
#define C1 8192                        // edges per block, partition passes

// ---- workspace layout (bytes) ----
static const size_t O_FLAG   = 0;                      // detect flag
static const size_t O_BCNT   = 256;                    // NB ints (bucket counts)
static const size_t O_BSTART = O_BCNT + 4096;          // NB+1 ints
static const size_t O_BCUR   = O_BSTART + 4096;        // NB ints
static const size_t O_WTL    = O_BCUR + 4096;
static const size_t O_WTR    = O_WTL + (size_t)D * D * 4;
static const size_t O_OFFS   = O_WTR + (size_t)D * D * 4;    // NN+1 ints
static const size_t O_DEG    = O_OFFS + (size_t)(NN + 64) * 4;  // Plan B only
static const size_t O_RECS   = O_DEG + (size_t)NN * 4;       // E packed records
// O_SRCS = O_RECS + E*4 (computed at launch)

// Detect whether edge_index buffer is int64 (odd int32 words zero) or int32.
__global__ void k_detect(const int* __restrict__ ei, int* flag) {
    if (threadIdx.x == 0 && blockIdx.x == 0) {
        int ok = 1;
        for (int j = 0; j < 128; ++j)
            if (ei[2 * j + 1] != 0) { ok = 0; break; }
        *flag = ok;
    }
}

__device__ __forceinline__ int edge_at(const int* ei, long long pos, int is64) {
    return is64 ? ei[2 * pos] : ei[pos];
}

// Transpose both weight matrices: Wt[k][o] = W[o][k]
__global__ void k_transpose(const float* __restrict__ Wl, const float* __restrict__ Wr,
                            float* __restrict__ WtL, float* __restrict__ WtR) {
    int t = blockIdx.x * 256 + threadIdx.x;
    if (t < D * D) {
        int o = t >> 7, k = t & 127;
        WtL[k * D + o] = Wl[t];
        WtR[k * D + o] = Wr[t];
    }
}

// Pass 1a: per-block LDS bucket histogram -> one global atomic per bucket/block.
__global__ __launch_bounds__(256) void k_p1count(const int* __restrict__ ei,
                                                 const int* __restrict__ flag,
                                                 int* __restrict__ bcount, long long E) {
    __shared__ int cnt[NB];
    for (int i = threadIdx.x; i < NB; i += 256) cnt[i] = 0;
    __syncthreads();
    int is64 = *flag;
    long long base = (long long)blockIdx.x * C1;
    for (int j = threadIdx.x; j < C1; j += 256) {
        long long e = base + j;
        if (e < E) {
            int d = edge_at(ei, E + e, is64);
            atomicAdd(&cnt[d >> 7], 1);
        }
    }
    __syncthreads();
    for (int i = threadIdx.x; i < NB; i += 256) {
        int c = cnt[i];
        if (c) atomicAdd(&bcount[i], c);
    }
}

// Exclusive scan of NB bucket counts (single block). Also writes offs[NN] = E.
__global__ __launch_bounds__(1024) void k_bscan(const int* __restrict__ bcount,
                                                int* __restrict__ bstart,
                                                int* __restrict__ bcur,
                                                int* __restrict__ offs) {
    __shared__ int sh[1024];
    int t = threadIdx.x;
    sh[t] = (t < NB) ? bcount[t] : 0;
    __syncthreads();
    for (int d = 1; d < 1024; d <<= 1) {
        int v = (t >= d) ? sh[t - d] : 0;
        __syncthreads();
        sh[t] += v;
        __syncthreads();
    }
    if (t < NB) {
        int ex = (t > 0) ? sh[t - 1] : 0;
        bstart[t] = ex;
        bcur[t] = ex;
    }
    if (t == NB - 1) {
        bstart[NB] = sh[NB - 1];
        offs[NN] = sh[NB - 1];     // total edge count = CSR sentinel
    }
}

// Pass 1b: scatter packed records (src | d_local<<20) into bucket regions.
__global__ __launch_bounds__(256) void k_p1scatter(const int* __restrict__ ei,
                                                   const int* __restrict__ flag,
                                                   int* __restrict__ bcur,
                                                   unsigned int* __restrict__ recs,
                                                   long long E) {
    __shared__ int cnt[NB];
    __shared__ int rbase[NB];
    for (int i = threadIdx.x; i < NB; i += 256) cnt[i] = 0;
    __syncthreads();
    int is64 = *flag;
    long long base = (long long)blockIdx.x * C1;
    for (int j = threadIdx.x; j < C1; j += 256) {
        long long e = base + j;
        if (e < E) {
            int d = edge_at(ei, E + e, is64);
            atomicAdd(&cnt[d >> 7], 1);
        }
    }
    __syncthreads();
    for (int i = threadIdx.x; i < NB; i += 256) {
        int c = cnt[i];
        rbase[i] = c ? atomicAdd(&bcur[i], c) : 0;
    }
    __syncthreads();
    for (int i = threadIdx.x; i < NB; i += 256) cnt[i] = 0;
    __syncthreads();
    for (int j = threadIdx.x; j < C1; j += 256) {
        long long e = base + j;
        if (e < E) {
            int s = edge_at(ei, e, is64);
            int d = edge_at(ei, E + e, is64);
            int bu = d >> 7;
            int pos = rbase[bu] + atomicAdd(&cnt[bu], 1);
            recs[pos] = (unsigned)s | ((unsigned)(d & (W0 - 1)) << 20);
        }
    }
}

// Pass 2: per bucket, bucket-sorted records -> exact per-node CSR.
__global__ __launch_bounds__(256) void k_p2(const unsigned int* __restrict__ recs,
                                            const int* __restrict__ bstart,
                                            int* __restrict__ offs,
                                            int* __restrict__ srcs, int N) {
    __shared__ int cnt[W0];
    __shared__ int off[W0];
    int t = threadIdx.x;
    int bu = blockIdx.x;
    int e0 = bstart[bu], e1 = bstart[bu + 1];
    if (t < W0) cnt[t] = 0;
    __syncthreads();
    for (int e = e0 + t; e < e1; e += 256)
        atomicAdd(&cnt[recs[e] >> 20], 1);
    __syncthreads();
    if (t < W0) off[t] = cnt[t];
    __syncthreads();
    for (int d = 1; d < W0; d <<= 1) {
        int v = 0;
        if (t < W0 && t >= d) v = off[t - d];
        __syncthreads();
        if (t < W0) off[t] += v;
        __syncthreads();
    }
    if (t < W0) {
        int ex = (t > 0) ? off[t - 1] : 0;
        int node = bu * W0 + t;
        if (node < N) offs[node] = e0 + ex;
        cnt[t] = e0 + ex;              // reuse as global write cursor
    }
    __syncthreads();
    for (int e = e0 + t; e < e1; e += 256) {
        unsigned r = recs[e];
        int pos = atomicAdd(&cnt[r >> 20], 1);
        srcs[pos] = (int)(r & 0xFFFFFu);
    }
}

// One wave per node: mean-aggregate neighbor rows into agg (= d_out).
__global__ __launch_bounds__(256) void k_agg(const float* __restrict__ x,
                                             const int* __restrict__ offs,
                                             const int* __restrict__ srcs,
                                             float* agg, int N) {
    int lane = threadIdx.x & 63;
    int wid = __builtin_amdgcn_readfirstlane(threadIdx.x >> 6);
    int node = blockIdx.x * 4 + wid;
    if (node >= N) return;
    int e0 = offs[node], e1 = offs[node + 1];
    const float2* x2 = (const float2*)x;
    float ax = 0.f, ay = 0.f;
    int e = e0;
    for (; e + 4 <= e1; e += 4) {
        int s0 = srcs[e], s1 = srcs[e + 1], s2 = srcs[e + 2], s3 = srcs[e + 3];
        float2 v0 = x2[(long long)s0 * 64 + lane];
        float2 v1 = x2[(long long)s1 * 64 + lane];
        float2 v2 = x2[(long long)s2 * 64 + lane];
        float2 v3 = x2[(long long)s3 * 64 + lane];
        ax += v0.x + v1.x + v2.x + v3.x;
        ay += v0.y + v1.y + v2.y + v3.y;
    }
    for (; e < e1; ++e) {
        int s = srcs[e];
        float2 v = x2[(long long)s * 64 + lane];
        ax += v.x; ay += v.y;
    }
    float inv = 1.0f / fmaxf((float)(e1 - e0), 1.0f);
    float2 o; o.x = ax * inv; o.y = ay * inv;
    ((float2*)agg)[(long long)node * 64 + lane] = o;
}

// Plan B: atomic scatter (one wave per edge) then mean.
__global__ __launch_bounds__(256) void k_scatterB(const float* __restrict__ x,
                                                  const int* __restrict__ ei,
                                                  const int* __restrict__ flag,
                                                  float* out, float* deg, long long E) {
    int lane = threadIdx.x & 63;
    long long e = (long long)blockIdx.x * 4 + (threadIdx.x >> 6);
    if (e >= E) return;
    int is64 = *flag;
    int s = edge_at(ei, e, is64);
    int d = edge_at(ei, E + e, is64);
    atomicAdd(&out[(long long)d * D + lane], x[(long long)s * D + lane]);
    atomicAdd(&out[(long long)d * D + 64 + lane], x[(long long)s * D + 64 + lane]);
    if (lane == 0) atomicAdd(&deg[d], 1.0f);
}

__global__ void k_meanB(float* out, const float* __restrict__ deg) {
    long long i = (long long)blockIdx.x * 256 + threadIdx.x;
    if (i >= (long long)NN * D) return;
    out[i] *= 1.0f / fmaxf(deg[i >> 7], 1.0f);
}

// Fused out = agg@Wl^T + b + x@Wr^T, then row L2-normalize.
// Block = 256 threads -> 64-row x 128-col tile. Thread = 4 rows x 8 cols,
// cols split as {tx*4..+3} and {64+tx*4..+3} (4-bank spacing -> 2-way LDS
// aliasing, free). W^T staged in 64-k-row halves (32 KB LDS -> 5 blocks/CU).
__global__ __launch_bounds__(256) void k_gemm(const float* __restrict__ x,
                                              const float* agg,
                                              const float* __restrict__ WtL,
                                              const float* __restrict__ WtR,
                                              const float* __restrict__ bl,
                                              float* out, int N) {
    __shared__ float Bs[64 * D];   // 32 KB: half of W^T, [k][col]
    int t = threadIdx.x;
    int tx = t & 15;
    int ty = t >> 4;
    int row0 = blockIdx.x * 64 + ty * 4;
    int c0a = tx * 4;
    int c0b = 64 + tx * 4;

    float acc[4][8];
    float4 b0 = *(const float4*)(bl + c0a);
    float4 b1 = *(const float4*)(bl + c0b);
#pragma unroll
    for (int r = 0; r < 4; ++r) {
        acc[r][0] = b0.x; acc[r][1] = b0.y; acc[r][2] = b0.z; acc[r][3] = b0.w;
        acc[r][4] = b1.x; acc[r][5] = b1.y; acc[r][6] = b1.z; acc[r][7] = b1.w;
    }

    long long rws[4];
#pragma unroll
    for (int r = 0; r < 4; ++r) {
        int rr = row0 + r;
        rws[r] = (rr < N) ? (long long)rr : (long long)(N - 1);
    }

    for (int phase = 0; phase < 2; ++phase) {
        const float* A = phase ? x : agg;
        const float* W = phase ? WtR : WtL;
        const float4* Ar0 = (const float4*)(A + rws[0] * D);
        const float4* Ar1 = (const float4*)(A + rws[1] * D);
        const float4* Ar2 = (const float4*)(A + rws[2] * D);
        const float4* Ar3 = (const float4*)(A + rws[3] * D);

        for (int half = 0; half < 2; ++half) {
            if (phase | half) __syncthreads();  // LDS reads (and phase-0 agg reads) done
#pragma unroll
            for (int i = 0; i < 8; ++i) {
                int idx = t + i * 256;
                ((float4*)Bs)[idx] = ((const float4*)(W + half * 64 * D))[idx];
            }
            __syncthreads();

#pragma unroll 2
            for (int k4 = 0; k4 < 16; ++k4) {
                int ak4 = half * 16 + k4;
                float4 av[4];
                av[0] = Ar0[ak4]; av[1] = Ar1[ak4]; av[2] = Ar2[ak4]; av[3] = Ar3[ak4];
#pragma unroll
                for (int kk = 0; kk < 4; ++kk) {
                    int k = k4 * 4 + kk;
                    float4 w0 = *(const float4*)&Bs[k * D + c0a];
                    float4 w1 = *(const float4*)&Bs[k * D + c0b];
#pragma unroll
                    for (int r = 0; r < 4; ++r) {
                        float a = (kk == 0) ? av[r].x : (kk == 1) ? av[r].y
                                 : (kk == 2) ? av[r].z : av[r].w;
                        acc[r][0] = fmaf(a, w0.x, acc[r][0]);
                        acc[r][1] = fmaf(a, w0.y, acc[r][1]);
                        acc[r][2] = fmaf(a, w0.z, acc[r][2]);
                        acc[r][3] = fmaf(a, w0.w, acc[r][3]);
                        acc[r][4] = fmaf(a, w1.x, acc[r][4]);
                        acc[r][5] = fmaf(a, w1.y, acc[r][5]);
                        acc[r][6] = fmaf(a, w1.z, acc[r][6]);
                        acc[r][7] = fmaf(a, w1.w, acc[r][7]);
                    }
                }
            }
        }
    }

#pragma unroll
    for (int r = 0; r < 4; ++r) {
        float s = 0.f;
#pragma unroll
        for (int j = 0; j < 8; ++j) s = fmaf(acc[r][j], acc[r][j], s);
        s += __shfl_xor(s, 1, 64);
        s += __shfl_xor(s, 2, 64);
        s += __shfl_xor(s, 4, 64);
        s += __shfl_xor(s, 8, 64);
        float scale = 1.0f / fmaxf(sqrtf(s), 1e-12f);
        int rr = row0 + r;
        if (rr < N) {
            float4 v0, v1;
            v0.x = acc[r][0] * scale; v0.y = acc[r][1] * scale;
            v0.z = acc[r][2] * scale; v0.w = acc[r][3] * scale;
            v1.x = acc[r][4] * scale; v1.y = acc[r][5] * scale;
            v1.z = acc[r][6] * scale; v1.w = acc[r][7] * scale;
            float* op = out + (long long)rr * D;
            *(float4*)(op + c0a) = v0;
            *(float4*)(op + c0b) = v1;
        }
    }
}

extern "C" void kernel_launch(void* const* d_in, const int* in_sizes, int n_in,
                              void* d_out, int out_size, void* d_ws, size_t ws_size,
                              hipStream_t stream) {
    const float* x  = (const float*)d_in[0];
    const int*   ei = (const int*)d_in[1];
    const float* Wl = (const float*)d_in[2];
    const float* bl = (const float*)d_in[3];
    const float* Wr = (const float*)d_in[4];
    float* out = (float*)d_out;
    const long long E = (long long)in_sizes[1] / 2;

    char* ws = (char*)d_ws;
    int*      flag   = (int*)(ws + O_FLAG);
    int*      bcount = (int*)(ws + O_BCNT);
    int*      bstart = (int*)(ws + O_BSTART);
    int*      bcur   = (int*)(ws + O_BCUR);
    float*    WtL    = (float*)(ws + O_WTL);
    float*    WtR    = (float*)(ws + O_WTR);
    int*      offs   = (int*)(ws + O_OFFS);
    float*    deg    = (float*)(ws + O_DEG);
    unsigned* recs   = (unsigned*)(ws + O_RECS);
    int*      srcs   = (int*)(ws + O_RECS + (size_t)E * 4);

    size_t planA_bytes = O_RECS + (size_t)E * 8;
    bool planA = ws_size >= planA_bytes;

    k_detect<<<1, 64, 0, stream>>>(ei, flag);
    k_transpose<<<(D * D + 255) / 256, 256, 0, stream>>>(Wl, Wr, WtL, WtR);

    if (planA) {
        int pblocks = (int)((E + C1 - 1) / C1);
        hipMemsetAsync(ws + O_BCNT, 0, (size_t)NB * 4, stream);
        k_p1count<<<pblocks, 256, 0, stream>>>(ei, flag, bcount, E);
        k_bscan<<<1, 1024, 0, stream>>>(bcount, bstart, bcur, offs);
        k_p1scatter<<<pblocks, 256, 0, stream>>>(ei, flag, bcur, recs, E);
        k_p2<<<NB, 256, 0, stream>>>(recs, bstart, offs, srcs, NN);
        k_agg<<<(NN + 3) / 4, 256, 0, stream>>>(x, offs, srcs, out, NN);
    } else {
        hipMemsetAsync(out, 0, (size_t)NN * D * 4, stream);
        hipMemsetAsync(ws + O_DEG, 0, (size_t)NN * 4, stream);
        k_scatterB<<<(int)((E + 3) / 4), 256, 0, stream>>>(x, ei, flag, out, deg, E);
        k_meanB<<<(int)(((long long)NN * D + 255) / 256), 256, 0, stream>>>(out, deg);
    }
    k_gemm<<<(NN + 63) / 64, 256, 0, stream>>>(x, out, WtL, WtR, bl, out, NN);
}

// Round 7
// 344.760 us; speedup vs baseline: 4.5698x; 1.0643x over previous
//
#include <hip/hip_runtime.h>
#include <hip/hip_fp16.h>
#include <stdint.h>

#define NN 100000
#define D 128
#define W0 128                         // nodes per bucket (power of 2)
#define NB ((NN + W0 - 1) / W0)        // 782 buckets
#define C1 8192                        // edges per block, partition passes

// ---- workspace layout (bytes) ----
static const size_t O_FLAG   = 0;                      // detect flag
static const size_t O_BCNT   = 256;                    // NB ints (bucket counts)
static const size_t O_BSTART = O_BCNT + 4096;          // NB+1 ints
static const size_t O_BCUR   = O_BSTART + 4096;        // NB ints
static const size_t O_WTL    = O_BCUR + 4096;
static const size_t O_WTR    = O_WTL + (size_t)D * D * 4;
static const size_t O_OFFS   = O_WTR + (size_t)D * D * 4;    // NN+1 ints
static const size_t O_DEG    = O_OFFS + (size_t)(NN + 64) * 4;  // Plan B only
static const size_t O_RECS   = O_DEG + (size_t)NN * 4;       // E packed records
// O_SRCS = O_RECS + E*4 ; O_XH = O_RECS + E*8 (computed at launch)

// Detect whether edge_index buffer is int64 (odd int32 words zero) or int32.
__global__ void k_detect(const int* __restrict__ ei, int* flag) {
    if (threadIdx.x == 0 && blockIdx.x == 0) {
        int ok = 1;
        for (int j = 0; j < 128; ++j)
            if (ei[2 * j + 1] != 0) { ok = 0; break; }
        *flag = ok;
    }
}

__device__ __forceinline__ int edge_at(const int* ei, long long pos, int is64) {
    return is64 ? ei[2 * pos] : ei[pos];
}

// Transpose both weight matrices: Wt[k][o] = W[o][k]
__global__ void k_transpose(const float* __restrict__ Wl, const float* __restrict__ Wr,
                            float* __restrict__ WtL, float* __restrict__ WtR) {
    int t = blockIdx.x * 256 + threadIdx.x;
    if (t < D * D) {
        int o = t >> 7, k = t & 127;
        WtL[k * D + o] = Wl[t];
        WtR[k * D + o] = Wr[t];
    }
}

// Convert x to fp16 (halves gather bytes in k_agg_h). 4 elems/thread.
__global__ __launch_bounds__(256) void k_conv(const float* __restrict__ x,
                                              __half* __restrict__ xh, long long n4) {
    long long i = (long long)blockIdx.x * 256 + threadIdx.x;
    if (i >= n4) return;
    float4 v = ((const float4*)x)[i];
    __half2 h0 = __floats2half2_rn(v.x, v.y);
    __half2 h1 = __floats2half2_rn(v.z, v.w);
    ((__half2*)xh)[2 * i]     = h0;
    ((__half2*)xh)[2 * i + 1] = h1;
}

// Pass 1a: per-block LDS bucket histogram -> one global atomic per bucket/block.
__global__ __launch_bounds__(256) void k_p1count(const int* __restrict__ ei,
                                                 const int* __restrict__ flag,
                                                 int* __restrict__ bcount, long long E) {
    __shared__ int cnt[NB];
    for (int i = threadIdx.x; i < NB; i += 256) cnt[i] = 0;
    __syncthreads();
    int is64 = *flag;
    long long base = (long long)blockIdx.x * C1;
    for (int j = threadIdx.x; j < C1; j += 256) {
        long long e = base + j;
        if (e < E) {
            int d = edge_at(ei, E + e, is64);
            atomicAdd(&cnt[d >> 7], 1);
        }
    }
    __syncthreads();
    for (int i = threadIdx.x; i < NB; i += 256) {
        int c = cnt[i];
        if (c) atomicAdd(&bcount[i], c);
    }
}

// Exclusive scan of NB bucket counts (single block). Also writes offs[NN] = E.
__global__ __launch_bounds__(1024) void k_bscan(const int* __restrict__ bcount,
                                                int* __restrict__ bstart,
                                                int* __restrict__ bcur,
                                                int* __restrict__ offs) {
    __shared__ int sh[1024];
    int t = threadIdx.x;
    sh[t] = (t < NB) ? bcount[t] : 0;
    __syncthreads();
    for (int d = 1; d < 1024; d <<= 1) {
        int v = (t >= d) ? sh[t - d] : 0;
        __syncthreads();
        sh[t] += v;
        __syncthreads();
    }
    if (t < NB) {
        int ex = (t > 0) ? sh[t - 1] : 0;
        bstart[t] = ex;
        bcur[t] = ex;
    }
    if (t == NB - 1) {
        bstart[NB] = sh[NB - 1];
        offs[NN] = sh[NB - 1];     // total edge count = CSR sentinel
    }
}

// Pass 1b: scatter packed records (src | d_local<<20) into bucket regions.
__global__ __launch_bounds__(256) void k_p1scatter(const int* __restrict__ ei,
                                                   const int* __restrict__ flag,
                                                   int* __restrict__ bcur,
                                                   unsigned int* __restrict__ recs,
                                                   long long E) {
    __shared__ int cnt[NB];
    __shared__ int rbase[NB];
    for (int i = threadIdx.x; i < NB; i += 256) cnt[i] = 0;
    __syncthreads();
    int is64 = *flag;
    long long base = (long long)blockIdx.x * C1;
    for (int j = threadIdx.x; j < C1; j += 256) {
        long long e = base + j;
        if (e < E) {
            int d = edge_at(ei, E + e, is64);
            atomicAdd(&cnt[d >> 7], 1);
        }
    }
    __syncthreads();
    for (int i = threadIdx.x; i < NB; i += 256) {
        int c = cnt[i];
        rbase[i] = c ? atomicAdd(&bcur[i], c) : 0;
    }
    __syncthreads();
    for (int i = threadIdx.x; i < NB; i += 256) cnt[i] = 0;
    __syncthreads();
    for (int j = threadIdx.x; j < C1; j += 256) {
        long long e = base + j;
        if (e < E) {
            int s = edge_at(ei, e, is64);
            int d = edge_at(ei, E + e, is64);
            int bu = d >> 7;
            int pos = rbase[bu] + atomicAdd(&cnt[bu], 1);
            recs[pos] = (unsigned)s | ((unsigned)(d & (W0 - 1)) << 20);
        }
    }
}

// Pass 2: per bucket, bucket-sorted records -> exact per-node CSR.
__global__ __launch_bounds__(256) void k_p2(const unsigned int* __restrict__ recs,
                                            const int* __restrict__ bstart,
                                            int* __restrict__ offs,
                                            int* __restrict__ srcs, int N) {
    __shared__ int cnt[W0];
    __shared__ int off[W0];
    int t = threadIdx.x;
    int bu = blockIdx.x;
    int e0 = bstart[bu], e1 = bstart[bu + 1];
    if (t < W0) cnt[t] = 0;
    __syncthreads();
    for (int e = e0 + t; e < e1; e += 256)
        atomicAdd(&cnt[recs[e] >> 20], 1);
    __syncthreads();
    if (t < W0) off[t] = cnt[t];
    __syncthreads();
    for (int d = 1; d < W0; d <<= 1) {
        int v = 0;
        if (t < W0 && t >= d) v = off[t - d];
        __syncthreads();
        if (t < W0) off[t] += v;
        __syncthreads();
    }
    if (t < W0) {
        int ex = (t > 0) ? off[t - 1] : 0;
        int node = bu * W0 + t;
        if (node < N) offs[node] = e0 + ex;
        cnt[t] = e0 + ex;              // reuse as global write cursor
    }
    __syncthreads();
    for (int e = e0 + t; e < e1; e += 256) {
        unsigned r = recs[e];
        int pos = atomicAdd(&cnt[r >> 20], 1);
        srcs[pos] = (int)(r & 0xFFFFFu);
    }
}

// One wave per node: mean-aggregate neighbor rows (fp16 x) into agg (= d_out).
__global__ __launch_bounds__(256) void k_agg_h(const __half* __restrict__ xh,
                                               const int* __restrict__ offs,
                                               const int* __restrict__ srcs,
                                               float* agg, int N) {
    int lane = threadIdx.x & 63;
    int wid = __builtin_amdgcn_readfirstlane(threadIdx.x >> 6);
    int node = blockIdx.x * 4 + wid;
    if (node >= N) return;
    int e0 = offs[node], e1 = offs[node + 1];
    const __half2* x2 = (const __half2*)xh;
    float ax = 0.f, ay = 0.f;
    int e = e0;
    for (; e + 4 <= e1; e += 4) {
        int s0 = srcs[e], s1 = srcs[e + 1], s2 = srcs[e + 2], s3 = srcs[e + 3];
        __half2 h0 = x2[(long long)s0 * 64 + lane];
        __half2 h1 = x2[(long long)s1 * 64 + lane];
        __half2 h2 = x2[(long long)s2 * 64 + lane];
        __half2 h3 = x2[(long long)s3 * 64 + lane];
        float2 v0 = __half22float2(h0);
        float2 v1 = __half22float2(h1);
        float2 v2 = __half22float2(h2);
        float2 v3 = __half22float2(h3);
        ax += v0.x + v1.x + v2.x + v3.x;
        ay += v0.y + v1.y + v2.y + v3.y;
    }
    for (; e < e1; ++e) {
        int s = srcs[e];
        float2 v = __half22float2(x2[(long long)s * 64 + lane]);
        ax += v.x; ay += v.y;
    }
    float inv = 1.0f / fmaxf((float)(e1 - e0), 1.0f);
    float2 o; o.x = ax * inv; o.y = ay * inv;
    ((float2*)agg)[(long long)node * 64 + lane] = o;
}

// f32 fallback (used when ws can't fit the fp16 copy).
__global__ __launch_bounds__(256) void k_agg(const float* __restrict__ x,
                                             const int* __restrict__ offs,
                                             const int* __restrict__ srcs,
                                             float* agg, int N) {
    int lane = threadIdx.x & 63;
    int wid = __builtin_amdgcn_readfirstlane(threadIdx.x >> 6);
    int node = blockIdx.x * 4 + wid;
    if (node >= N) return;
    int e0 = offs[node], e1 = offs[node + 1];
    const float2* x2 = (const float2*)x;
    float ax = 0.f, ay = 0.f;
    int e = e0;
    for (; e + 4 <= e1; e += 4) {
        int s0 = srcs[e], s1 = srcs[e + 1], s2 = srcs[e + 2], s3 = srcs[e + 3];
        float2 v0 = x2[(long long)s0 * 64 + lane];
        float2 v1 = x2[(long long)s1 * 64 + lane];
        float2 v2 = x2[(long long)s2 * 64 + lane];
        float2 v3 = x2[(long long)s3 * 64 + lane];
        ax += v0.x + v1.x + v2.x + v3.x;
        ay += v0.y + v1.y + v2.y + v3.y;
    }
    for (; e < e1; ++e) {
        int s = srcs[e];
        float2 v = x2[(long long)s * 64 + lane];
        ax += v.x; ay += v.y;
    }
    float inv = 1.0f / fmaxf((float)(e1 - e0), 1.0f);
    float2 o; o.x = ax * inv; o.y = ay * inv;
    ((float2*)agg)[(long long)node * 64 + lane] = o;
}

// Plan B: atomic scatter (one wave per edge) then mean.
__global__ __launch_bounds__(256) void k_scatterB(const float* __restrict__ x,
                                                  const int* __restrict__ ei,
                                                  const int* __restrict__ flag,
                                                  float* out, float* deg, long long E) {
    int lane = threadIdx.x & 63;
    long long e = (long long)blockIdx.x * 4 + (threadIdx.x >> 6);
    if (e >= E) return;
    int is64 = *flag;
    int s = edge_at(ei, e, is64);
    int d = edge_at(ei, E + e, is64);
    atomicAdd(&out[(long long)d * D + lane], x[(long long)s * D + lane]);
    atomicAdd(&out[(long long)d * D + 64 + lane], x[(long long)s * D + 64 + lane]);
    if (lane == 0) atomicAdd(&deg[d], 1.0f);
}

__global__ void k_meanB(float* out, const float* __restrict__ deg) {
    long long i = (long long)blockIdx.x * 256 + threadIdx.x;
    if (i >= (long long)NN * D) return;
    out[i] *= 1.0f / fmaxf(deg[i >> 7], 1.0f);
}

// Fused out = agg@Wl^T + b + x@Wr^T, then row L2-normalize.
__global__ __launch_bounds__(256) void k_gemm(const float* __restrict__ x,
                                              const float* agg,
                                              const float* __restrict__ WtL,
                                              const float* __restrict__ WtR,
                                              const float* __restrict__ bl,
                                              float* out, int N) {
    __shared__ float Bs[64 * D];   // 32 KB: half of W^T, [k][col]
    int t = threadIdx.x;
    int tx = t & 15;
    int ty = t >> 4;
    int row0 = blockIdx.x * 64 + ty * 4;
    int c0a = tx * 4;
    int c0b = 64 + tx * 4;

    float acc[4][8];
    float4 b0 = *(const float4*)(bl + c0a);
    float4 b1 = *(const float4*)(bl + c0b);
#pragma unroll
    for (int r = 0; r < 4; ++r) {
        acc[r][0] = b0.x; acc[r][1] = b0.y; acc[r][2] = b0.z; acc[r][3] = b0.w;
        acc[r][4] = b1.x; acc[r][5] = b1.y; acc[r][6] = b1.z; acc[r][7] = b1.w;
    }

    long long rws[4];
#pragma unroll
    for (int r = 0; r < 4; ++r) {
        int rr = row0 + r;
        rws[r] = (rr < N) ? (long long)rr : (long long)(N - 1);
    }

    for (int phase = 0; phase < 2; ++phase) {
        const float* A = phase ? x : agg;
        const float* W = phase ? WtR : WtL;
        const float4* Ar0 = (const float4*)(A + rws[0] * D);
        const float4* Ar1 = (const float4*)(A + rws[1] * D);
        const float4* Ar2 = (const float4*)(A + rws[2] * D);
        const float4* Ar3 = (const float4*)(A + rws[3] * D);

        for (int half = 0; half < 2; ++half) {
            if (phase | half) __syncthreads();
#pragma unroll
            for (int i = 0; i < 8; ++i) {
                int idx = t + i * 256;
                ((float4*)Bs)[idx] = ((const float4*)(W + half * 64 * D))[idx];
            }
            __syncthreads();

#pragma unroll 2
            for (int k4 = 0; k4 < 16; ++k4) {
                int ak4 = half * 16 + k4;
                float4 av[4];
                av[0] = Ar0[ak4]; av[1] = Ar1[ak4]; av[2] = Ar2[ak4]; av[3] = Ar3[ak4];
#pragma unroll
                for (int kk = 0; kk < 4; ++kk) {
                    int k = k4 * 4 + kk;
                    float4 w0 = *(const float4*)&Bs[k * D + c0a];
                    float4 w1 = *(const float4*)&Bs[k * D + c0b];
#pragma unroll
                    for (int r = 0; r < 4; ++r) {
                        float a = (kk == 0) ? av[r].x : (kk == 1) ? av[r].y
                                 : (kk == 2) ? av[r].z : av[r].w;
                        acc[r][0] = fmaf(a, w0.x, acc[r][0]);
                        acc[r][1] = fmaf(a, w0.y, acc[r][1]);
                        acc[r][2] = fmaf(a, w0.z, acc[r][2]);
                        acc[r][3] = fmaf(a, w0.w, acc[r][3]);
                        acc[r][4] = fmaf(a, w1.x, acc[r][4]);
                        acc[r][5] = fmaf(a, w1.y, acc[r][5]);
                        acc[r][6] = fmaf(a, w1.z, acc[r][6]);
                        acc[r][7] = fmaf(a, w1.w, acc[r][7]);
                    }
                }
            }
        }
    }

#pragma unroll
    for (int r = 0; r < 4; ++r) {
        float s = 0.f;
#pragma unroll
        for (int j = 0; j < 8; ++j) s = fmaf(acc[r][j], acc[r][j], s);
        s += __shfl_xor(s, 1, 64);
        s += __shfl_xor(s, 2, 64);
        s += __shfl_xor(s, 4, 64);
        s += __shfl_xor(s, 8, 64);
        float scale = 1.0f / fmaxf(sqrtf(s), 1e-12f);
        int rr = row0 + r;
        if (rr < N) {
            float4 v0, v1;
            v0.x = acc[r][0] * scale; v0.y = acc[r][1] * scale;
            v0.z = acc[r][2] * scale; v0.w = acc[r][3] * scale;
            v1.x = acc[r][4] * scale; v1.y = acc[r][5] * scale;
            v1.z = acc[r][6] * scale; v1.w = acc[r][7] * scale;
            float* op = out + (long long)rr * D;
            *(float4*)(op + c0a) = v0;
            *(float4*)(op + c0b) = v1;
        }
    }
}

extern "C" void kernel_launch(void* const* d_in, const int* in_sizes, int n_in,
                              void* d_out, int out_size, void* d_ws, size_t ws_size,
                              hipStream_t stream) {
    const float* x  = (const float*)d_in[0];
    const int*   ei = (const int*)d_in[1];
    const float* Wl = (const float*)d_in[2];
    const float* bl = (const float*)d_in[3];
    const float* Wr = (const float*)d_in[4];
    float* out = (float*)d_out;
    const long long E = (long long)in_sizes[1] / 2;

    char* ws = (char*)d_ws;
    int*      flag   = (int*)(ws + O_FLAG);
    int*      bcount = (int*)(ws + O_BCNT);
    int*      bstart = (int*)(ws + O_BSTART);
    int*      bcur   = (int*)(ws + O_BCUR);
    float*    WtL    = (float*)(ws + O_WTL);
    float*    WtR    = (float*)(ws + O_WTR);
    int*      offs   = (int*)(ws + O_OFFS);
    float*    deg    = (float*)(ws + O_DEG);
    unsigned* recs   = (unsigned*)(ws + O_RECS);
    int*      srcs   = (int*)(ws + O_RECS + (size_t)E * 4);
    const size_t O_XH = O_RECS + (size_t)E * 8;
    __half*   xh     = (__half*)(ws + O_XH);

    size_t planA_bytes = O_RECS + (size_t)E * 8;
    size_t fp16_bytes  = O_XH + (size_t)NN * D * 2;
    bool planA = ws_size >= planA_bytes;
    bool useH  = ws_size >= fp16_bytes;

    k_detect<<<1, 64, 0, stream>>>(ei, flag);
    k_transpose<<<(D * D + 255) / 256, 256, 0, stream>>>(Wl, Wr, WtL, WtR);

    if (planA) {
        int pblocks = (int)((E + C1 - 1) / C1);
        hipMemsetAsync(ws + O_BCNT, 0, (size_t)NB * 4, stream);
        if (useH) {
            long long n4 = (long long)NN * D / 4;
            k_conv<<<(int)((n4 + 255) / 256), 256, 0, stream>>>(x, xh, n4);
        }
        k_p1count<<<pblocks, 256, 0, stream>>>(ei, flag, bcount, E);
        k_bscan<<<1, 1024, 0, stream>>>(bcount, bstart, bcur, offs);
        k_p1scatter<<<pblocks, 256, 0, stream>>>(ei, flag, bcur, recs, E);
        k_p2<<<NB, 256, 0, stream>>>(recs, bstart, offs, srcs, NN);
        if (useH)
            k_agg_h<<<(NN + 3) / 4, 256, 0, stream>>>(xh, offs, srcs, out, NN);
        else
            k_agg<<<(NN + 3) / 4, 256, 0, stream>>>(x, offs, srcs, out, NN);
    } else {
        hipMemsetAsync(out, 0, (size_t)NN * D * 4, stream);
        hipMemsetAsync(ws + O_DEG, 0, (size_t)NN * 4, stream);
        k_scatterB<<<(int)((E + 3) / 4), 256, 0, stream>>>(x, ei, flag, out, deg, E);
        k_meanB<<<(int)(((long long)NN * D + 255) / 256), 256, 0, stream>>>(out, deg);
    }
    k_gemm<<<(NN + 63) / 64, 256, 0, stream>>>(x, out, WtL, WtR, bl, out, NN);
}